// Round 6
// baseline (77.974 us; speedup 1.0000x reference)
//
#include <hip/hip_runtime.h>
#include <stdint.h>

// ResidualAttentionBlock: L1-distance attention, 16x511 tokens, 8 heads x 64.
// R6: attn = 512-thr blocks, 8 waves: waves 0-3 keys [0,256) / waves 4-7 keys
//     [256,511) for the same four Q=64 tiles; in-block f16 combine through LDS.
//     Fixes R5's 1-wave/SIMD latency exposure (42us, no TLP) while keeping
//     Q=64 LDS amortization (8.2k b128/CU) and the XOR-swizzled K banks.
// Quantization: u = clamp(rint(256*x)+128,0,255); logit = -sad/2048;
// p = 2^(sad * -log2(e)/2048). Validated absmax 0.0156 (thr 0.099).

#define B  16
#define H  8
#define T  511

typedef __fp16 f16x2 __attribute__((ext_vector_type(2)));
typedef __fp16 f16x8 __attribute__((ext_vector_type(8)));
typedef float  f32x4 __attribute__((ext_vector_type(4)));

#if __has_builtin(__builtin_amdgcn_exp2f)
#define EXP2F(x) __builtin_amdgcn_exp2f(x)
#else
#define EXP2F(x) exp2f(x)
#endif

__device__ __forceinline__ uint32_t SAD(uint32_t a, uint32_t b, uint32_t c) {
#if __has_builtin(__builtin_amdgcn_sad_u8)
  return __builtin_amdgcn_sad_u8(a, b, c);
#else
  uint32_t d;
  asm("v_sad_u8 %0, %1, %2, %3" : "=v"(d) : "v"(a), "v"(b), "v"(c));
  return d;
#endif
}

__device__ __forceinline__ uint32_t PKRTZ(float a, float b) {
  f16x2 r = __builtin_amdgcn_cvt_pkrtz(a, b);
  return __builtin_bit_cast(uint32_t, r);
}

__device__ __forceinline__ uint32_t quantu8(float v) {
  float q = __builtin_rintf(__builtin_fmaf(v, 256.f, 128.f));
  q = fminf(fmaxf(q, 0.f), 255.f);
  return (uint32_t)(int)q;
}

// ---------------- weight transpose: wt[k][1024], wft[k][64] ----------------
__global__ void wtrans_kernel(const float* __restrict__ wq, const float* __restrict__ wv,
                              const float* __restrict__ wf, float* __restrict__ wt,
                              float* __restrict__ bias, float* __restrict__ wft,
                              float* __restrict__ biasf) {
  const int idx = blockIdx.x * 256 + (int)threadIdx.x;
  if (idx < 64 * 1024) {
    const int k = idx >> 10, j = idx & 1023;
    const float* src = (j < 512) ? wq : wv;
    const int oc = j & 511;
    wt[idx] = src[oc * 65 + k];
    if (k == 0) bias[j] = src[oc * 65 + 64];
  } else if (idx < 64 * 1024 + 64 * 64) {
    const int r = idx - 64 * 1024;
    const int k = r >> 6, w = r & 63;
    wft[r] = wf[w * 65 + k];
    if (k == 0) biasf[w] = wf[w * 65 + 64];
  }
}

// ------- projection: q->u8 [bh][T][64], v->f16 vt[bh][64][512], + makek ----
__global__ void __launch_bounds__(256, 2) proj_kernel(
    const float* __restrict__ x, const float* __restrict__ wt,
    const float* __restrict__ bias, const float* __restrict__ wk,
    uint8_t* __restrict__ qq, _Float16* __restrict__ vt,
    uint8_t* __restrict__ kq) {
  __shared__ float xt[64][16];  // [k][tok]
  const int b = blockIdx.y, tc = blockIdx.x;
  const int t0 = tc * 16;
  const int tid = threadIdx.x;
  {
    const int tl = tid >> 4, k0 = (tid & 15) * 4;
    const int t = t0 + tl;
    float4 v = {0.f, 0.f, 0.f, 0.f};
    if (t < T) v = *(const float4*)(x + ((size_t)b * T + t) * 64 + k0);
    xt[k0 + 0][tl] = v.x; xt[k0 + 1][tl] = v.y;
    xt[k0 + 2][tl] = v.z; xt[k0 + 3][tl] = v.w;
  }
  __syncthreads();
  const int j0 = tid * 4;
  const float4 bs = *(const float4*)(bias + j0);
  float4 acc[16];
#pragma unroll
  for (int t = 0; t < 16; ++t) acc[t] = bs;
  for (int k = 0; k < 64; ++k) {
    const float4 w4 = *(const float4*)(wt + (size_t)k * 1024 + j0);
    const float4* xr = (const float4*)xt[k];
    const float4 xa = xr[0], xb = xr[1], xc = xr[2], xd = xr[3];
    const float xv[16] = {xa.x, xa.y, xa.z, xa.w, xb.x, xb.y, xb.z, xb.w,
                          xc.x, xc.y, xc.z, xc.w, xd.x, xd.y, xd.z, xd.w};
#pragma unroll
    for (int t = 0; t < 16; ++t) {
      acc[t].x = __builtin_fmaf(w4.x, xv[t], acc[t].x);
      acc[t].y = __builtin_fmaf(w4.y, xv[t], acc[t].y);
      acc[t].z = __builtin_fmaf(w4.z, xv[t], acc[t].z);
      acc[t].w = __builtin_fmaf(w4.w, xv[t], acc[t].w);
    }
  }
  const int oc = j0 & 511;
  const int hh = oc >> 6, w0 = oc & 63;
  const size_t bh = (size_t)b * H + hh;
  if (j0 < 512) {  // q side
#pragma unroll
    for (int t = 0; t < 16; ++t) {
      if (t0 + t < T) {
        const uint32_t u = quantu8(acc[t].x) | (quantu8(acc[t].y) << 8) |
                           (quantu8(acc[t].z) << 16) | (quantu8(acc[t].w) << 24);
        *(uint32_t*)(qq + (bh * T + (size_t)(t0 + t)) * 64 + w0) = u;
      }
    }
  } else {  // v side -> transposed vt[bh][w][512]
#pragma unroll
    for (int i = 0; i < 4; ++i) {
      uint32_t u[8];
      const float* a = (const float*)acc;  // acc[t][i] = a[4t+i]
#pragma unroll
      for (int m = 0; m < 8; ++m) u[m] = PKRTZ(a[4 * (2 * m) + i], a[4 * (2 * m + 1) + i]);
      _Float16* p = vt + (bh * 64 + (size_t)(w0 + i)) * 512 + t0;
      *(uint4*)(p)     = make_uint4(u[0], u[1], u[2], u[3]);
      *(uint4*)(p + 8) = make_uint4(u[4], u[5], u[6], u[7]);
    }
  }
  // ---- fused makek: kq[b][h][t][w] = quant(x[t][w] * wk[h][w]) ----
  const int tk = tid >> 4, w4 = (tid & 15) * 4;
  if (t0 + tk < T) {
    const float xv0 = xt[w4 + 0][tk], xv1 = xt[w4 + 1][tk];
    const float xv2 = xt[w4 + 2][tk], xv3 = xt[w4 + 3][tk];
#pragma unroll
    for (int hh2 = 0; hh2 < H; ++hh2) {
      const float4 wkv = *(const float4*)(wk + hh2 * 64 + w4);
      const uint32_t u = quantu8(xv0 * wkv.x) | (quantu8(xv1 * wkv.y) << 8) |
                         (quantu8(xv2 * wkv.z) << 16) | (quantu8(xv3 * wkv.w) << 24);
      *(uint32_t*)(kq + (((size_t)b * H + hh2) * T + (size_t)(t0 + tk)) * 64 + w4) = u;
    }
  }
}

// ------ fused L1 attention: swizzled LDS K + Q=64/wave + key-split ---------
// grid (2, H, B), 512 thr = 8 waves. Wave w: q-tile (w&3), keys
// [(w>>2)*256, ...+256). Upper waves pass (num f16, den) via LDS; lower
// waves combine + normalize + store. K row chunk j at slot j^((s>>3)&3).
__global__ void __launch_bounds__(512, 2) attn_kernel(
    const uint8_t* __restrict__ qq, const uint8_t* __restrict__ kq,
    const _Float16* __restrict__ vt, _Float16* __restrict__ anum) {
  __shared__ uint4 klds[2048];       // 32 KB K; reused for f16 num combine
  __shared__ float dend[4][4][16];   // [pair][m][c] upper-half den
  const int qt = blockIdx.x, h = blockIdx.y, b = blockIdx.z;
  const int bh = b * H + h;
  const int tid = threadIdx.x;
  {
    const uint4* kg = (const uint4*)(kq + (size_t)bh * T * 64);
    for (int i = tid; i < T * 4; i += 512) {
      const int s = i >> 2, j = i & 3;
      klds[s * 4 + (j ^ ((s >> 3) & 3))] = kg[i];
    }
  }
  const int wave = tid >> 6, lane = tid & 63;
  const int pair = wave & 3, khalf = wave >> 2;
  const int c = lane & 15, g = lane >> 4;
  const int qb = qt * 256 + pair * 64;
  uint4 q[4][4];
#pragma unroll
  for (int m = 0; m < 4; ++m) {
    const int qm = qb + 16 * m + c;
    const int qsafe = qm < T ? qm : T - 1;
    const uint4* qp = (const uint4*)(qq + ((size_t)bh * T + qsafe) * 64);
#pragma unroll
    for (int i = 0; i < 4; ++i) q[m][i] = qp[i];
  }
  const _Float16* vb = vt + (size_t)bh * 64 * 512;
  f32x4 acc[4][4];
#pragma unroll
  for (int m = 0; m < 4; ++m)
#pragma unroll
    for (int nt = 0; nt < 4; ++nt) acc[m][nt] = f32x4{0.f, 0.f, 0.f, 0.f};
  float den[4] = {0.f, 0.f, 0.f, 0.f};
  const float Cl = -0x1.715476p+0f / 2048.0f;  // -log2(e)/2048
  __syncthreads();

#pragma unroll 1
  for (int kt = 0; kt < 8; ++kt) {
    const int ks = khalf * 256 + kt * 32;
    // V B-frags (shared by all 4 A-tiles), issued early to hide L2 latency.
    const _Float16* vp0 = vb + (size_t)c * 512 + ks + g * 8;
    uint4 bvec[4];
#pragma unroll
    for (int nt = 0; nt < 4; ++nt) bvec[nt] = *(const uint4*)(vp0 + nt * 16 * 512);
    uint32_t pk[4][4];  // [tile][jj]
#pragma unroll
    for (int jj = 0; jj < 4; ++jj) {
      float pp[4][2];
#pragma unroll
      for (int e = 0; e < 2; ++e) {
        const int s = ks + g * 8 + jj * 2 + e;
        const int sr = s < T ? s : T - 1;
        const uint4* kp = klds + sr * 4;
        const int bb = (sr >> 3) & 3;
        const uint4 k0 = kp[bb], k1 = kp[1 ^ bb], k2 = kp[2 ^ bb], k3 = kp[3 ^ bb];
        const bool live = s < T;
#pragma unroll
        for (int m = 0; m < 4; ++m) {
          uint32_t a0 = 0, a1 = 0;
          a0 = SAD(q[m][0].x, k0.x, a0); a0 = SAD(q[m][0].y, k0.y, a0);
          a0 = SAD(q[m][0].z, k0.z, a0); a0 = SAD(q[m][0].w, k0.w, a0);
          a0 = SAD(q[m][1].x, k1.x, a0); a0 = SAD(q[m][1].y, k1.y, a0);
          a0 = SAD(q[m][1].z, k1.z, a0); a0 = SAD(q[m][1].w, k1.w, a0);
          a1 = SAD(q[m][2].x, k2.x, a1); a1 = SAD(q[m][2].y, k2.y, a1);
          a1 = SAD(q[m][2].z, k2.z, a1); a1 = SAD(q[m][2].w, k2.w, a1);
          a1 = SAD(q[m][3].x, k3.x, a1); a1 = SAD(q[m][3].y, k3.y, a1);
          a1 = SAD(q[m][3].z, k3.z, a1); a1 = SAD(q[m][3].w, k3.w, a1);
          const float p = EXP2F((float)(a0 + a1) * Cl);
          pp[m][e] = live ? p : 0.f;
        }
      }
#pragma unroll
      for (int m = 0; m < 4; ++m) {
        den[m] += pp[m][0] + pp[m][1];
        pk[m][jj] = PKRTZ(pp[m][0], pp[m][1]);
      }
    }
#pragma unroll
    for (int m = 0; m < 4; ++m) {
      const f16x8 af = __builtin_bit_cast(f16x8, make_uint4(pk[m][0], pk[m][1], pk[m][2], pk[m][3]));
#pragma unroll
      for (int nt = 0; nt < 4; ++nt) {
        const f16x8 bf = __builtin_bit_cast(f16x8, bvec[nt]);
        acc[m][nt] = __builtin_amdgcn_mfma_f32_16x16x32_f16(af, bf, acc[m][nt], 0, 0, 0);
      }
    }
  }

  // den: reduce over the 4 lane-groups (keys split g-wise within the wave).
#pragma unroll
  for (int m = 0; m < 4; ++m) {
    den[m] += __shfl_xor(den[m], 16, 64);
    den[m] += __shfl_xor(den[m], 32, 64);
  }

  __syncthreads();  // K reads done; klds becomes the num-combine buffer
  uint32_t* scr = (uint32_t*)klds;  // scr[j*256 + pair*64 + lane], bank = lane
  if (khalf) {
#pragma unroll
    for (int m = 0; m < 4; ++m) {
      if (g == 0) dend[pair][m][c] = den[m];
#pragma unroll
      for (int nt = 0; nt < 4; ++nt) {
        const int j = m * 8 + nt * 2;
        scr[j * 256 + pair * 64 + lane]       = PKRTZ(acc[m][nt][0], acc[m][nt][1]);
        scr[(j + 1) * 256 + pair * 64 + lane] = PKRTZ(acc[m][nt][2], acc[m][nt][3]);
      }
    }
  }
  __syncthreads();
  if (!khalf) {
    float dtot[4];
#pragma unroll
    for (int m = 0; m < 4; ++m) dtot[m] = den[m] + dend[pair][m][c] + 1.0f;  // + sink
#pragma unroll
    for (int m = 0; m < 4; ++m) {
#pragma unroll
      for (int nt = 0; nt < 4; ++nt) {
        const int j = m * 8 + nt * 2;
        const f16x2 u0 = __builtin_bit_cast(f16x2, scr[j * 256 + pair * 64 + lane]);
        const f16x2 u1 = __builtin_bit_cast(f16x2, scr[(j + 1) * 256 + pair * 64 + lane]);
        acc[m][nt][0] += (float)u0[0]; acc[m][nt][1] += (float)u0[1];
        acc[m][nt][2] += (float)u1[0]; acc[m][nt][3] += (float)u1[1];
      }
    }
#pragma unroll
    for (int m = 0; m < 4; ++m) {
#pragma unroll
      for (int r = 0; r < 4; ++r) {
        const float rd = 1.0f / __shfl(dtot[m], g * 4 + r, 64);
        const int qr = qb + 16 * m + g * 4 + r;
        if (qr < T) {
          _Float16* ap = anum + (((size_t)b * T + qr) * H + h) * 64 + c;
          ap[0]  = (_Float16)(acc[m][0][r] * rd);
          ap[16] = (_Float16)(acc[m][1][r] * rd);
          ap[32] = (_Float16)(acc[m][2][r] * rd);
          ap[48] = (_Float16)(acc[m][3][r] * rd);
        }
      }
    }
  }
}

// ---------------- finalize: sum heads, relu, fanout, residual --------------
__global__ void __launch_bounds__(256) finalize_kernel(
    const float* __restrict__ x, const _Float16* __restrict__ anum,
    const float* __restrict__ wft, const float* __restrict__ biasf,
    float* __restrict__ out) {
  __shared__ float u[4][64];
  const int tid = threadIdx.x;
  const int lt = tid >> 6, w = tid & 63;
  const int gt = blockIdx.x * 4 + lt;  // B*T = 8176 = 2044*4 exactly
  const _Float16* an = anum + (size_t)gt * H * 64 + w;
  float s = 0.f;
#pragma unroll
  for (int hh = 0; hh < H; ++hh) s += (float)an[hh * 64];
  u[lt][w] = fmaxf(s, 0.f);
  __syncthreads();
  float y = biasf[w];
#pragma unroll 8
  for (int k = 0; k < 64; ++k) y = __builtin_fmaf(wft[k * 64 + w], u[lt][k], y);
  out[(size_t)gt * 64 + w] = x[(size_t)gt * 64 + w] + y;
}

extern "C" void kernel_launch(void* const* d_in, const int* in_sizes, int n_in,
                              void* d_out, int out_size, void* d_ws, size_t ws_size,
                              hipStream_t stream) {
  (void)in_sizes; (void)n_in; (void)out_size; (void)ws_size;
  const float* x  = (const float*)d_in[0];
  const float* wq = (const float*)d_in[1];
  const float* wv = (const float*)d_in[2];
  const float* wk = (const float*)d_in[3];
  const float* wf = (const float*)d_in[4];
  float* out = (float*)d_out;

  uint8_t* ws = (uint8_t*)d_ws;
  // byte offsets (all 16B-aligned); total ~25.4 MB
  const size_t o_qq   = 0;                       // B*H*T*64 u8   = 4,186,112
  const size_t o_kq   = 4186112;                 // B*H*T*64 u8   = 4,186,112
  const size_t o_vt   = 8372224;                 // B*H*64*512 f16= 8,388,608
  const size_t o_anum = 16760832;                // B*T*H*64 f16  = 8,372,224
  const size_t o_wt   = 25133056;                // 64*1024 f32   =   262,144
  const size_t o_bias = 25395200;                // 1024 f32
  const size_t o_wft  = 25399296;                // 64*64 f32
  const size_t o_bf   = 25415680;                // 64 f32

  uint8_t*  qq    = ws + o_qq;
  uint8_t*  kq    = ws + o_kq;
  _Float16* vt    = (_Float16*)(ws + o_vt);
  _Float16* anum  = (_Float16*)(ws + o_anum);
  float*    wt    = (float*)(ws + o_wt);
  float*    bias  = (float*)(ws + o_bias);
  float*    wft   = (float*)(ws + o_wft);
  float*    biasf = (float*)(ws + o_bf);

  wtrans_kernel<<<dim3((64 * 1024 + 64 * 64 + 255) / 256), 256, 0, stream>>>(
      wq, wv, wf, wt, bias, wft, biasf);
  proj_kernel<<<dim3(32, B), 256, 0, stream>>>(x, wt, bias, wk, qq, vt, kq);
  attn_kernel<<<dim3(2, H, B), 512, 0, stream>>>(qq, kq, vt, anum);
  finalize_kernel<<<dim3(B * T / 4), 256, 0, stream>>>(x, anum, wft, biasf, out);
}